// Round 1
// baseline (345.997 us; speedup 1.0000x reference)
//
#include <hip/hip_runtime.h>

// VectorQuantizer: x [32,64,4096] f32, emb [512,64] f32.
// N = 32*4096 = 131072 vectors (n = b*T + t), D = 64, K = 512.
// out[0 .. N*D)      : quantized flat = emb[idx[i/64]][i%64]
// out[N*D]           : loss = 1.25 * mean((q_flat - x_flat_linear)^2)
// argmin_k ( ||e_k||^2 - 2*x.e_k )  (||x||^2 constant per row, dropped)

#define VQ_D 64
#define VQ_K 512
#define VQ_T 4096
#define VQ_N 131072
#define VQ_OUTQ 8388608   // N*D

__global__ __launch_bounds__(256) void vq_main(
    const float* __restrict__ x,
    const float* __restrict__ emb,
    float* __restrict__ qout,
    double* __restrict__ loss_acc)
{
    __shared__ float cks[VQ_K];     // ||e_k||^2
    __shared__ float wsum[4];

    const float4* __restrict__ emb4 = (const float4*)emb;

    // --- precompute codeword norms (once per block; 2 rows/thread) ---
    for (int k = threadIdx.x; k < VQ_K; k += 256) {
        float c = 0.f;
        #pragma unroll
        for (int i = 0; i < 16; ++i) {
            float4 e = emb4[k * 16 + i];
            c = fmaf(e.x, e.x, c);
            c = fmaf(e.y, e.y, c);
            c = fmaf(e.z, e.z, c);
            c = fmaf(e.w, e.w, c);
        }
        cks[k] = c;
    }
    __syncthreads();

    const int n = blockIdx.x * 256 + threadIdx.x;   // vector id, n = b*T + t
    const int b = n >> 12;                          // / 4096
    const int t = n & 4095;

    // --- load this thread's x vector (strided: x[b, d, t]) ---
    const float* __restrict__ xp = x + b * (VQ_D * VQ_T) + t;
    float xv[VQ_D];
    #pragma unroll
    for (int d = 0; d < VQ_D; ++d) xv[d] = xp[d * VQ_T];

    // --- argmin over 512 codewords ---
    float best = 3.0e38f;
    int bi = 0;
    #pragma unroll 2
    for (int k = 0; k < VQ_K; ++k) {
        const float4* __restrict__ ep = emb4 + k * 16;
        float s0 = 0.f, s1 = 0.f, s2 = 0.f, s3 = 0.f;
        #pragma unroll
        for (int q = 0; q < 4; ++q) {
            float4 e0 = ep[0 * 4 + q];
            float4 e1 = ep[1 * 4 + q];
            float4 e2 = ep[2 * 4 + q];
            float4 e3 = ep[3 * 4 + q];
            s0 = fmaf(xv[ 0 + q * 4 + 0], e0.x, s0);
            s0 = fmaf(xv[ 0 + q * 4 + 1], e0.y, s0);
            s0 = fmaf(xv[ 0 + q * 4 + 2], e0.z, s0);
            s0 = fmaf(xv[ 0 + q * 4 + 3], e0.w, s0);
            s1 = fmaf(xv[16 + q * 4 + 0], e1.x, s1);
            s1 = fmaf(xv[16 + q * 4 + 1], e1.y, s1);
            s1 = fmaf(xv[16 + q * 4 + 2], e1.z, s1);
            s1 = fmaf(xv[16 + q * 4 + 3], e1.w, s1);
            s2 = fmaf(xv[32 + q * 4 + 0], e2.x, s2);
            s2 = fmaf(xv[32 + q * 4 + 1], e2.y, s2);
            s2 = fmaf(xv[32 + q * 4 + 2], e2.z, s2);
            s2 = fmaf(xv[32 + q * 4 + 3], e2.w, s2);
            s3 = fmaf(xv[48 + q * 4 + 0], e3.x, s3);
            s3 = fmaf(xv[48 + q * 4 + 1], e3.y, s3);
            s3 = fmaf(xv[48 + q * 4 + 2], e3.z, s3);
            s3 = fmaf(xv[48 + q * 4 + 3], e3.w, s3);
        }
        float dot = (s0 + s1) + (s2 + s3);
        float dist = fmaf(-2.f, dot, cks[k]);
        if (dist < best) { best = dist; bi = k; }   // strict <: first-min tie-break
    }

    // --- write quantized (flat [n,64]) + fused loss partial vs linear x ---
    const float4* __restrict__ eb = emb4 + bi * 16;
    const float4* __restrict__ xl = (const float4*)x + n * 16;
    float4* __restrict__ qo = (float4*)qout + n * 16;
    float lsum = 0.f;
    #pragma unroll
    for (int i = 0; i < 16; ++i) {
        float4 qv = eb[i];
        float4 xr = xl[i];
        qo[i] = qv;
        float dx = qv.x - xr.x;
        float dy = qv.y - xr.y;
        float dz = qv.z - xr.z;
        float dw = qv.w - xr.w;
        lsum = fmaf(dx, dx, lsum);
        lsum = fmaf(dy, dy, lsum);
        lsum = fmaf(dz, dz, lsum);
        lsum = fmaf(dw, dw, lsum);
    }

    // wave(64) shuffle reduce
    #pragma unroll
    for (int off = 32; off > 0; off >>= 1)
        lsum += __shfl_down(lsum, off, 64);
    if ((threadIdx.x & 63) == 0) wsum[threadIdx.x >> 6] = lsum;
    __syncthreads();
    if (threadIdx.x == 0) {
        double s = (double)wsum[0] + (double)wsum[1]
                 + (double)wsum[2] + (double)wsum[3];
        atomicAdd(loss_acc, s);
    }
}

__global__ void vq_finalize(const double* __restrict__ acc,
                            float* __restrict__ out)
{
    out[VQ_OUTQ] = (float)(1.25 * acc[0] / (double)VQ_OUTQ);
}

extern "C" void kernel_launch(void* const* d_in, const int* in_sizes, int n_in,
                              void* d_out, int out_size, void* d_ws, size_t ws_size,
                              hipStream_t stream)
{
    const float* x   = (const float*)d_in[0];   // 8388608
    const float* emb = (const float*)d_in[1];   // 32768
    float* out = (float*)d_out;                 // 8388609
    double* acc = (double*)d_ws;

    hipMemsetAsync(d_ws, 0, sizeof(double), stream);
    vq_main<<<dim3(VQ_N / 256), dim3(256), 0, stream>>>(x, emb, out, acc);
    vq_finalize<<<dim3(1), dim3(1), 0, stream>>>(acc, out);
}

// Round 2
// 123.299 us; speedup vs baseline: 2.8062x; 2.8062x over previous
//
#include <hip/hip_runtime.h>

// VectorQuantizer via bf16 MFMA distance GEMM.
// x [32,64,4096] f32, emb [512,64] f32.  N = 131072 rows (n = b*4096 + t), D=64, K=512.
// dist(n,k) = ||e_k||^2 - 2 * x_n . e_k   (||x||^2 dropped; fp32 norms, bf16 dot)
// out[0..N*64)  = emb[argmin][d]  (exact fp32 emb values)
// out[N*64]     = 1.25 * mean((q_flat - x_linear)^2)

#define VQ_N 131072
#define VQ_OUTQ 8388608

typedef __attribute__((ext_vector_type(8))) short short8;
typedef __attribute__((ext_vector_type(4))) float f32x4;

__device__ __forceinline__ short f2bf(float f) {
    union { float f; unsigned u; } c; c.f = f;
    unsigned u = c.u;
    unsigned r = (u + 0x7FFFu + ((u >> 16) & 1u)) >> 16;   // RNE
    return (short)r;
}

// LDS row stride: 72 shorts = 144 B (16B-aligned rows, bank-uniform b128 access)
#define LSTR 72

__global__ __launch_bounds__(512, 2) void vq_main(
    const float* __restrict__ x,
    const float* __restrict__ emb,
    float* __restrict__ qout,
    double* __restrict__ lacc)
{
    __shared__ __align__(16) short xbf[512 * LSTR];   // 73728 B: x-tile bf16, [row][d]
    __shared__ __align__(16) short ebf[512 * LSTR];   // 73728 B: emb bf16,   [k][d]
    __shared__ float cks[512];                        // ||e_k||^2 fp32
    __shared__ int   idxs[512];
    __shared__ float wsum[8];

    const int tid = threadIdx.x;
    const int b  = blockIdx.x >> 3;
    const int t0 = (blockIdx.x & 7) << 9;             // 512-row t-tile

    // ---- stage emb -> bf16 LDS + fp32 norms (1 row / thread) ----
    {
        const float4* __restrict__ er = (const float4*)emb + tid * 16;
        float ck = 0.f;
        #pragma unroll
        for (int i = 0; i < 16; i += 2) {
            float4 p0 = er[i], p1 = er[i + 1];
            ck = fmaf(p0.x, p0.x, ck); ck = fmaf(p0.y, p0.y, ck);
            ck = fmaf(p0.z, p0.z, ck); ck = fmaf(p0.w, p0.w, ck);
            ck = fmaf(p1.x, p1.x, ck); ck = fmaf(p1.y, p1.y, ck);
            ck = fmaf(p1.z, p1.z, ck); ck = fmaf(p1.w, p1.w, ck);
            short8 s;
            s[0] = f2bf(p0.x); s[1] = f2bf(p0.y); s[2] = f2bf(p0.z); s[3] = f2bf(p0.w);
            s[4] = f2bf(p1.x); s[5] = f2bf(p1.y); s[6] = f2bf(p1.z); s[7] = f2bf(p1.w);
            *(short8*)&ebf[tid * LSTR + i * 4] = s;
        }
        cks[tid] = ck;
    }

    // ---- stage x-tile transposed -> bf16 LDS (row = t-local, col = d) ----
    {
        const float* __restrict__ xb = x + (size_t)b * 262144 + t0 + tid;
        #pragma unroll
        for (int db = 0; db < 64; db += 8) {
            short8 s;
            #pragma unroll
            for (int j = 0; j < 8; ++j)
                s[j] = f2bf(xb[(size_t)(db + j) * 4096]);
            *(short8*)&xbf[tid * LSTR + db] = s;
        }
    }
    __syncthreads();

    // ---- MFMA distance + running argmin; wave owns 64 rows ----
    const int lane = tid & 63, wave = tid >> 6;
    const int m = lane & 15, quad = lane >> 4;
    const int wbase = wave << 6;

    short8 a[4][2];
    #pragma unroll
    for (int rt = 0; rt < 4; ++rt) {
        const int row = wbase + rt * 16 + m;
        a[rt][0] = *(const short8*)&xbf[row * LSTR + quad * 8];
        a[rt][1] = *(const short8*)&xbf[row * LSTR + 32 + quad * 8];
    }

    float best[4][4]; int bid[4][4];
    #pragma unroll
    for (int rt = 0; rt < 4; ++rt)
        #pragma unroll
        for (int r = 0; r < 4; ++r) { best[rt][r] = 3.0e38f; bid[rt][r] = 0; }

    #pragma unroll 2
    for (int ct = 0; ct < 32; ++ct) {
        const int cod = (ct << 4) + m;                 // this lane's codeword column
        short8 b0 = *(const short8*)&ebf[cod * LSTR + quad * 8];
        short8 b1 = *(const short8*)&ebf[cod * LSTR + 32 + quad * 8];
        float ck = cks[cod];
        #pragma unroll
        for (int rt = 0; rt < 4; ++rt) {
            f32x4 acc = {0.f, 0.f, 0.f, 0.f};
            acc = __builtin_amdgcn_mfma_f32_16x16x32_bf16(a[rt][0], b0, acc, 0, 0, 0);
            acc = __builtin_amdgcn_mfma_f32_16x16x32_bf16(a[rt][1], b1, acc, 0, 0, 0);
            #pragma unroll
            for (int r = 0; r < 4; ++r) {
                float dist = fmaf(-2.f, acc[r], ck);
                if (dist < best[rt][r]) { best[rt][r] = dist; bid[rt][r] = cod; }
            }
        }
    }

    // ---- cross-lane argmin within each 16-lane row group (tie -> lowest idx) ----
    #pragma unroll
    for (int rt = 0; rt < 4; ++rt) {
        #pragma unroll
        for (int r = 0; r < 4; ++r) {
            float bv = best[rt][r]; int bi = bid[rt][r];
            #pragma unroll
            for (int mm = 1; mm < 16; mm <<= 1) {
                float ov = __shfl_xor(bv, mm, 64);
                int   oi = __shfl_xor(bi, mm, 64);
                if (ov < bv || (ov == bv && oi < bi)) { bv = ov; bi = oi; }
            }
            if (m == 0) idxs[wbase + rt * 16 + (quad << 2) + r] = bi;
        }
    }
    __syncthreads();

    // ---- write quantized rows (exact fp32 emb) + fused loss vs linear x ----
    {
        const int bi = idxs[tid];
        const size_t n = ((size_t)b << 12) + t0 + tid;
        const float4* __restrict__ eb = (const float4*)emb + bi * 16;
        const float4* __restrict__ xl = (const float4*)x + n * 16;
        float4* __restrict__ qo = (float4*)qout + n * 16;
        float ls = 0.f;
        #pragma unroll
        for (int i = 0; i < 16; ++i) {
            float4 q = eb[i];
            float4 xr = xl[i];
            qo[i] = q;
            float dx = q.x - xr.x, dy = q.y - xr.y;
            float dz = q.z - xr.z, dw = q.w - xr.w;
            ls = fmaf(dx, dx, ls); ls = fmaf(dy, dy, ls);
            ls = fmaf(dz, dz, ls); ls = fmaf(dw, dw, ls);
        }
        #pragma unroll
        for (int off = 32; off > 0; off >>= 1)
            ls += __shfl_down(ls, off, 64);
        if (lane == 0) wsum[wave] = ls;
    }
    __syncthreads();
    if (tid == 0) {
        double s = 0.0;
        #pragma unroll
        for (int w = 0; w < 8; ++w) s += (double)wsum[w];
        atomicAdd(lacc, s);
    }
}

__global__ void vq_finalize(const double* __restrict__ acc,
                            float* __restrict__ out)
{
    out[VQ_OUTQ] = (float)(1.25 * acc[0] / (double)VQ_OUTQ);
}

extern "C" void kernel_launch(void* const* d_in, const int* in_sizes, int n_in,
                              void* d_out, int out_size, void* d_ws, size_t ws_size,
                              hipStream_t stream)
{
    const float* x   = (const float*)d_in[0];
    const float* emb = (const float*)d_in[1];
    float* out = (float*)d_out;
    double* acc = (double*)d_ws;

    hipMemsetAsync(d_ws, 0, sizeof(double), stream);
    vq_main<<<dim3(256), dim3(512), 0, stream>>>(x, emb, out, acc);
    vq_finalize<<<dim3(1), dim3(1), 0, stream>>>(acc, out);
}